// Round 1
// baseline (886.506 us; speedup 1.0000x reference)
//
#include <hip/hip_runtime.h>

// BoundingBoxDiscipline: bbox of (max over C > thr) masks for pred/true,
// per-batch area + center penalties, scalar mean output.
//
// Shapes fixed by the reference: B=16, H=256, W=256, C=128, fp32.
// Algorithmic core: bbox needs only min/max over row_any / col_any, and both
// the per-pixel mask (any channel > thr) and the per-row/col "any" admit
// short-circuit evaluation. For uniform random inputs each probe terminates
// at its first pixel -> ~8 MiB traffic instead of 1 GiB.

#define BB 16
#define HH 256
#define WW 256
#define CC 128
#define THR_PRED 0.3f
#define THR_TRUE 0.5f

// ws layout: [b][tensor] x {ymin, ymax, xmin, xmax} = 16*2*4 = 128 ints.

__global__ void bbox_init_ws(int* __restrict__ ws) {
    int i = threadIdx.x;  // 0..127
    if (i < BB * 2 * 4) {
        int f = i & 3;
        int v;
        if (f == 0) v = HH;        // ymin: min-identity
        else if (f == 1) v = -1;   // ymax: max-identity
        else if (f == 2) v = WW;   // xmin
        else v = -1;               // xmax
        ws[i] = v;
    }
}

// One wave per task. Task id bits: [b:4][tensor:1][mode:1][idx:8]
// mode 0 = row probe (scan x, update ymin/ymax), mode 1 = col probe.
__global__ __launch_bounds__(256) void bbox_probe(const float* __restrict__ pred,
                                                  const float* __restrict__ truth,
                                                  int* __restrict__ ws) {
    const int wave = (blockIdx.x * 256 + threadIdx.x) >> 6;
    const int lane = threadIdx.x & 63;

    const int idx  = wave & 255;
    const int mode = (wave >> 8) & 1;
    const int a    = (wave >> 9) & 1;
    const int b    = wave >> 10;

    const float* __restrict__ arr = a ? truth : pred;
    const float thr = a ? THR_TRUE : THR_PRED;
    int* box = ws + ((b * 2 + a) << 2);

    if (mode == 0) {
        // Row `idx`: scan pixels x = 0..W-1, short-circuit at first true pixel.
        const long long rowbase = ((long long)(b * HH + idx) * WW) * CC;
        for (int x = 0; x < WW; ++x) {
            // 64 lanes x float2 = all 128 channels of pixel (idx, x), coalesced 512B.
            const float2 v = *(const float2*)(arr + rowbase + (long long)x * CC + 2 * lane);
            const bool hit = (v.x > thr) || (v.y > thr);
            if (__any(hit)) {
                if (lane == 0) {
                    atomicMin(box + 0, idx);
                    atomicMax(box + 1, idx);
                }
                break;
            }
        }
    } else {
        // Column `idx`: scan pixels y = 0..H-1.
        const long long colbase = ((long long)b * HH * WW + idx) * CC;
        for (int y = 0; y < HH; ++y) {
            const float2 v = *(const float2*)(arr + colbase + (long long)y * WW * CC + 2 * lane);
            const bool hit = (v.x > thr) || (v.y > thr);
            if (__any(hit)) {
                if (lane == 0) {
                    atomicMin(box + 2, idx);
                    atomicMax(box + 3, idx);
                }
                break;
            }
        }
    }
}

__global__ void bbox_finalize(const int* __restrict__ ws, float* __restrict__ out) {
    __shared__ float pen[BB];
    const int b = threadIdx.x;
    if (b < BB) {
        const int* pb = ws + ((b * 2 + 0) << 2);
        const int* tb = ws + ((b * 2 + 1) << 2);

        // Reference box order: (y_min, x_min, y_max, x_max); empty -> (0,0,1,1).
        const bool pe = pb[1] < 0;
        const float p0 = pe ? 0.f : (float)pb[0];
        const float p1 = pe ? 0.f : (float)pb[2];
        const float p2 = pe ? 1.f : (float)pb[1];
        const float p3 = pe ? 1.f : (float)pb[3];
        const bool te = tb[1] < 0;
        const float t0 = te ? 0.f : (float)tb[0];
        const float t1 = te ? 0.f : (float)tb[2];
        const float t2 = te ? 1.f : (float)tb[1];
        const float t3 = te ? 1.f : (float)tb[3];

        const float pred_area = (p2 - p0 + 1.f) * (p3 - p1 + 1.f);
        const float true_area = (t2 - t0 + 1.f) * (t3 - t1 + 1.f);
        const float area_pen  = fmaxf(pred_area - true_area, 0.f) / (true_area + 1.f);

        const float dy = (p0 + p2) * 0.5f - (t0 + t2) * 0.5f;
        const float dx = (p1 + p3) * 0.5f - (t1 + t3) * 0.5f;
        const float center = sqrtf(dy * dy + dx * dx) / 20.f;

        pen[b] = area_pen + center;
    }
    __syncthreads();
    if (threadIdx.x == 0) {
        float s = 0.f;
        for (int i = 0; i < BB; ++i) s += pen[i];
        out[0] = 0.05f * (s / (float)BB);
    }
}

extern "C" void kernel_launch(void* const* d_in, const int* in_sizes, int n_in,
                              void* d_out, int out_size, void* d_ws, size_t ws_size,
                              hipStream_t stream) {
    const float* pred  = (const float*)d_in[0];
    const float* truth = (const float*)d_in[1];
    int* ws = (int*)d_ws;
    float* out = (float*)d_out;

    bbox_init_ws<<<1, 128, 0, stream>>>(ws);
    // 16 batches * 2 tensors * 2 modes * 256 indices = 16384 waves; 4 waves/block.
    bbox_probe<<<4096, 256, 0, stream>>>(pred, truth, ws);
    bbox_finalize<<<1, 64, 0, stream>>>(ws, out);
}

// Round 2
// 768.660 us; speedup vs baseline: 1.1533x; 1.1533x over previous
//
#include <hip/hip_runtime.h>

// BoundingBoxDiscipline: bbox of (max over C > thr) masks for pred/true,
// per-batch area + center penalties, scalar mean output.
//
// Shapes fixed by the reference: B=16, H=256, W=256, C=128, fp32.
// Strategy: bbox needs only min/max over row_any / col_any. Both the
// per-pixel mask (any channel > thr) and per-row/col "any" short-circuit:
// one wave per (batch, tensor, row|col, index) probes pixels until the
// first hit (first pixel w.p. ~1 for uniform inputs) and writes a flag.
// A single-block finalize reduces flags -> boxes -> penalties -> scalar.
// No atomics, no ws init needed (every flag slot written unconditionally).

#define BB 16
#define HH 256
#define WW 256
#define CC 128
#define THR_PRED 0.3f
#define THR_TRUE 0.5f

// ws layout: flags[((b*2 + a)*2 + mode)*256 + idx], 16*2*2*256 = 16384 ints.
// mode 0 = row flags (row_any[y]), mode 1 = col flags (col_any[x]).

__global__ __launch_bounds__(256) void bbox_probe(const float* __restrict__ pred,
                                                  const float* __restrict__ truth,
                                                  int* __restrict__ flags) {
    const int wave = (blockIdx.x * 256 + threadIdx.x) >> 6;
    const int lane = threadIdx.x & 63;

    const int idx  = wave & 255;
    const int mode = (wave >> 8) & 1;
    const int a    = (wave >> 9) & 1;
    const int b    = wave >> 10;

    const float* __restrict__ arr = a ? truth : pred;
    const float thr = a ? THR_TRUE : THR_PRED;

    // Pixel stride along the scan direction.
    const long long step = (mode == 0) ? (long long)CC : (long long)WW * CC;
    const long long base = (mode == 0)
        ? ((long long)(b * HH + idx) * WW) * CC        // row idx, scan x
        : ((long long)b * HH * WW + idx) * CC;         // col idx, scan y

    int flag = 0;
    for (int i = 0; i < 256; ++i) {
        const float* pix = arr + base + step * i;
        // Channels 0..63 (256B coalesced). Misses with prob <= 0.5^64.
        if (__any(pix[lane] > thr)) { flag = 1; break; }
        // Rare fallback: channels 64..127.
        if (__any(pix[64 + lane] > thr)) { flag = 1; break; }
    }
    if (lane == 0) flags[wave] = flag;
}

__global__ __launch_bounds__(1024) void bbox_finalize(const int* __restrict__ flags,
                                                      float* __restrict__ out) {
    // 32 groups g = b*2 + a; rows at flags[g*512 + 0..255], cols at +256.
    __shared__ int sbox[32][4];  // ymin, ymax, xmin, xmax
    const int waveid = threadIdx.x >> 6;
    const int lane   = threadIdx.x & 63;

    for (int g = waveid; g < 32; g += 16) {
        const int* rf = flags + g * 512;
        const int* cf = rf + 256;
        int ymin = HH, ymax = -1, xmin = WW, xmax = -1;
        for (int j = lane; j < 256; j += 64) {
            if (rf[j]) { ymin = min(ymin, j); ymax = max(ymax, j); }
            if (cf[j]) { xmin = min(xmin, j); xmax = max(xmax, j); }
        }
        for (int off = 32; off > 0; off >>= 1) {
            ymin = min(ymin, __shfl_down(ymin, off));
            ymax = max(ymax, __shfl_down(ymax, off));
            xmin = min(xmin, __shfl_down(xmin, off));
            xmax = max(xmax, __shfl_down(xmax, off));
        }
        if (lane == 0) {
            sbox[g][0] = ymin; sbox[g][1] = ymax;
            sbox[g][2] = xmin; sbox[g][3] = xmax;
        }
    }
    __syncthreads();

    if (waveid == 0) {
        float pen = 0.f;
        if (lane < BB) {
            const int b = lane;
            const int* pb = sbox[b * 2 + 0];
            const int* tb = sbox[b * 2 + 1];
            // Empty mask -> (y_min,x_min,y_max,x_max) = (0,0,1,1).
            const bool pe = pb[1] < 0;
            const float py0 = pe ? 0.f : (float)pb[0];
            const float py1 = pe ? 1.f : (float)pb[1];
            const float px0 = pe ? 0.f : (float)pb[2];
            const float px1 = pe ? 1.f : (float)pb[3];
            const bool te = tb[1] < 0;
            const float ty0 = te ? 0.f : (float)tb[0];
            const float ty1 = te ? 1.f : (float)tb[1];
            const float tx0 = te ? 0.f : (float)tb[2];
            const float tx1 = te ? 1.f : (float)tb[3];

            const float pred_area = (py1 - py0 + 1.f) * (px1 - px0 + 1.f);
            const float true_area = (ty1 - ty0 + 1.f) * (tx1 - tx0 + 1.f);
            const float area_pen  = fmaxf(pred_area - true_area, 0.f) / (true_area + 1.f);

            const float dy = (py0 + py1) * 0.5f - (ty0 + ty1) * 0.5f;
            const float dx = (px0 + px1) * 0.5f - (tx0 + tx1) * 0.5f;
            pen = area_pen + sqrtf(dy * dy + dx * dx) / 20.f;
        }
        for (int off = 32; off > 0; off >>= 1) pen += __shfl_down(pen, off);
        if (lane == 0) out[0] = 0.05f * (pen / (float)BB);
    }
}

extern "C" void kernel_launch(void* const* d_in, const int* in_sizes, int n_in,
                              void* d_out, int out_size, void* d_ws, size_t ws_size,
                              hipStream_t stream) {
    const float* pred  = (const float*)d_in[0];
    const float* truth = (const float*)d_in[1];
    int* flags = (int*)d_ws;
    float* out = (float*)d_out;

    // 16 batches * 2 tensors * 2 modes * 256 indices = 16384 waves; 4/block.
    bbox_probe<<<4096, 256, 0, stream>>>(pred, truth, flags);
    bbox_finalize<<<1, 1024, 0, stream>>>(flags, out);
}